// Round 8
// baseline (448.254 us; speedup 1.0000x reference)
//
#include <hip/hip_runtime.h>
#include <hip/hip_fp16.h>

// ---------------------------------------------------------------------------
// 3-layer GCN + linear head.  N=50000 nodes, E=800000 edges, D=128.
// Normalization factored: GEMM writes y16 = dinv*(z@W); CSR stores raw w
// (4 B packed); agg: out = b + dinv_i*(y16_i + sum w*y16_src).
// Aggregation is feature-sliced (4 slices of 32 cols) with XCD affinity
// (slice = blockIdx & 3; round-robin block->XCD puts slice s on XCD s/s+4),
// so each XCD's random-gather working set (3.2 MB column slice) fits its
// private 4 MiB L2.
// ---------------------------------------------------------------------------

#define D 128

typedef __attribute__((ext_vector_type(8))) _Float16 half8;
typedef __attribute__((ext_vector_type(4))) float floatx4;

#define CNT_STRIDE 16   // one u32 counter per 64 B cache line

// ---- pass 1: count edges per dst; old count -> per-edge CSR slot ----------
__global__ __launch_bounds__(256) void k_edge_pass1(const int* __restrict__ dst,
                                                    unsigned int* __restrict__ cntp,
                                                    int* __restrict__ loc, int E) {
    int e = blockIdx.x * 256 + threadIdx.x;
    if (e < E) {
        int d = dst[e];
        loc[e] = (int)atomicAdd(&cntp[(size_t)d * CNT_STRIDE], 1u);
    }
}

// ---- block-wide exclusive scan helper (256 threads) -----------------------
__device__ inline int block_exscan_256(int v) {
    int tid = threadIdx.x;
    int lane = tid & 63, wv = tid >> 6;
    int incl = v;
#pragma unroll
    for (int d = 1; d < 64; d <<= 1) {
        int n = __shfl_up(incl, d, 64);
        if (lane >= d) incl += n;
    }
    __shared__ int wsum[4];
    if (lane == 63) wsum[wv] = incl;
    __syncthreads();
    int woff = 0;
#pragma unroll
    for (int j = 0; j < 4; j++) woff += (j < wv) ? wsum[j] : 0;
    return woff + incl - v;
}

__global__ __launch_bounds__(256) void k_scan_a(const unsigned int* __restrict__ cntp,
                                                int* bsum, int N) {
    int i = blockIdx.x * 256 + threadIdx.x;
    int v = (i < N) ? (int)cntp[(size_t)i * CNT_STRIDE] : 0;
#pragma unroll
    for (int d = 32; d; d >>= 1) v += __shfl_down(v, d, 64);
    __shared__ int ws4[4];
    int lane = threadIdx.x & 63, wv = threadIdx.x >> 6;
    if (lane == 0) ws4[wv] = v;
    __syncthreads();
    if (threadIdx.x == 0) bsum[blockIdx.x] = ws4[0] + ws4[1] + ws4[2] + ws4[3];
}

__global__ __launch_bounds__(256) void k_scan_b(const int* __restrict__ bsum,
                                                int* boff, int nb) {
    int tid = threadIdx.x;
    int v = (tid < nb) ? bsum[tid] : 0;
    int ex = block_exscan_256(v);
    if (tid < nb) boff[tid] = ex;
}

__global__ __launch_bounds__(256) void k_scan_c(const unsigned int* __restrict__ cntp,
                                                const int* __restrict__ boff,
                                                int* rp, int N, int E) {
    int i = blockIdx.x * 256 + threadIdx.x;
    int v = (i < N) ? (int)cntp[(size_t)i * CNT_STRIDE] : 0;
    int ex = block_exscan_256(v);
    if (i < N) rp[i] = boff[blockIdx.x] + ex;
    if (i == 0) rp[N] = E;
}

// ---- CSR fill: ev[p] = (w_q15 << 17) | src  (4 B per edge, no gathers) ----
__global__ __launch_bounds__(256) void k_fill(const int* __restrict__ ei,
                                              const float* __restrict__ w,
                                              const int* __restrict__ rp,
                                              const int* __restrict__ loc,
                                              unsigned int* __restrict__ ev, int E) {
    int e = blockIdx.x * 256 + threadIdx.x;
    if (e < E) {
        int s = ei[e];
        int d = ei[E + e];
        int p = rp[d] + loc[e];
        unsigned int wq = (unsigned int)__float2uint_rn(w[e] * 32767.0f);
        ev[p] = (wq << 17) | (unsigned int)s;
    }
}

// ---- weighted degree from CSR; dinv = rsqrt(1 + sum w) --------------------
__global__ __launch_bounds__(256) void k_deg(const int* __restrict__ rp,
                                             const unsigned int* __restrict__ ev,
                                             float* __restrict__ dinv, int N) {
    int i = blockIdx.x * 256 + threadIdx.x;
    if (i < N) {
        int e0 = rp[i], e1 = rp[i + 1];
        float s = 0.f;
        for (int e = e0; e < e1; e++)
            s += (float)(ev[e] >> 17);
        dinv[i] = rsqrtf(1.0f + s * (1.0f / 32767.0f));
    }
}

// ---- MFMA GEMM: y = A @ W ; optional row scale by dinv; optional bias -----
// 128 rows/block (4 waves x 32 rows), v_mfma_f32_16x16x32_f16, fp32 accum.
// W staged transposed as fp16 in LDS (Wl[n][k], pad->136). A fragments from
// global (read exactly once). Layouts (m89/m91): A[m=lane&15][k=quad*8+j],
// B[k=quad*8+j][n=lane&15], C/D col=lane&15, row=quad*4+reg.
template <bool A_IS_F32>
__global__ __launch_bounds__(256) void k_gemm_mfma(const void* __restrict__ Aptr,
                                                   const float* __restrict__ W,
                                                   const float* __restrict__ dinv,
                                                   const float* __restrict__ bias,
                                                   float* __restrict__ C32,
                                                   __half* __restrict__ C16, int N) {
    __shared__ _Float16 Wl[128][136];
    int tid = threadIdx.x;

#pragma unroll
    for (int j = 0; j < 64; j++) {
        int e = tid + j * 256;          // 16384 elements
        int k = e >> 7, n = e & 127;
        Wl[n][k] = (_Float16)W[e];
    }
    __syncthreads();

    int wave = tid >> 6, lane = tid & 63;
    int m = lane & 15, q = lane >> 4;
    int R0 = blockIdx.x * 128 + wave * 32;   // row tiles R0, R0+16

    const float*  A32p = (const float*)Aptr;
    const __half* A16p = (const __half*)Aptr;

    floatx4 acc[2][8];
#pragma unroll
    for (int rt = 0; rt < 2; rt++)
#pragma unroll
        for (int ct = 0; ct < 8; ct++) acc[rt][ct] = (floatx4){0.f, 0.f, 0.f, 0.f};

#pragma unroll
    for (int kk = 0; kk < 4; kk++) {
        half8 a[2];
#pragma unroll
        for (int rt = 0; rt < 2; rt++) {
            int row = R0 + rt * 16 + m;
            half8 t = {0, 0, 0, 0, 0, 0, 0, 0};
            if (row < N) {
                if (A_IS_F32) {
                    const float* p = &A32p[(size_t)row * 128 + kk * 32 + q * 8];
                    float4 f0 = *(const float4*)p;
                    float4 f1 = *(const float4*)(p + 4);
                    t[0] = (_Float16)f0.x; t[1] = (_Float16)f0.y;
                    t[2] = (_Float16)f0.z; t[3] = (_Float16)f0.w;
                    t[4] = (_Float16)f1.x; t[5] = (_Float16)f1.y;
                    t[6] = (_Float16)f1.z; t[7] = (_Float16)f1.w;
                } else {
                    t = *(const half8*)&A16p[(size_t)row * 128 + kk * 32 + q * 8];
                }
            }
            a[rt] = t;
        }
#pragma unroll
        for (int ct = 0; ct < 8; ct++) {
            half8 b = *(const half8*)&Wl[ct * 16 + m][kk * 32 + q * 8];
            acc[0][ct] = __builtin_amdgcn_mfma_f32_16x16x32_f16(a[0], b, acc[0][ct], 0, 0, 0);
            acc[1][ct] = __builtin_amdgcn_mfma_f32_16x16x32_f16(a[1], b, acc[1][ct], 0, 0, 0);
        }
    }

    // epilogue: C/D col=lane&15 (=m), row=quad*4+reg
#pragma unroll
    for (int rt = 0; rt < 2; rt++) {
#pragma unroll
        for (int r = 0; r < 4; r++) {
            int row = R0 + rt * 16 + q * 4 + r;
            if (row >= N) continue;
            float dv = (dinv != nullptr) ? dinv[row] : 1.0f;
#pragma unroll
            for (int ct = 0; ct < 8; ct++) {
                int col = ct * 16 + m;
                float v = acc[rt][ct][r] * dv;
                if (C16) C16[(size_t)row * 128 + col] = __float2half_rn(v);
                if (C32) C32[(size_t)row * 128 + col] = v + bias[col];
            }
        }
    }
}

// ---- sliced aggregation: out_i = b + dinv_i*(y16_i + sum w*y16_src) -------
// Block b: nodes ng*4..ng*4+3 (one per wave), feature slice s = b & 3
// (32 cols = 64 B). Round-robin block->XCD dispatch puts slice s on XCDs
// {s, s+4} only, so each XCD's gather set is a 3.2 MB column slice (fits L2).
// Within a wave: 8 groups x 8 lanes; group g handles edge e+g; lane sl
// (0..7) covers 4 fp16 features (uint2 = 8 B); 8 edges in flight.
__global__ __launch_bounds__(256) void k_agg(const __half* __restrict__ y16,
                                             const int* __restrict__ rp,
                                             const unsigned int* __restrict__ ev,
                                             const float* __restrict__ dinv,
                                             const float* __restrict__ bias,
                                             __half* __restrict__ out16,
                                             int N, int relu) {
    int s = blockIdx.x & 3;                       // feature slice
    int i = (blockIdx.x >> 2) * 4 + (threadIdx.x >> 6);   // node
    if (i >= N) return;
    int lane = threadIdx.x & 63;
    int g = lane >> 3;        // edge group 0..7
    int sl = lane & 7;        // feature sub-slot (4 fp16)
    int fo = s * 32 + sl * 4; // feature offset within row

    float a0 = 0.f, a1 = 0.f, a2 = 0.f, a3 = 0.f;

    int e0 = rp[i], e1 = rp[i + 1];
    int e = e0;

#define GFMA(P)                                                           \
    {                                                                     \
        int   c = (int)((P) & 0x1FFFFu);                                  \
        float v = (float)((P) >> 17) * (1.0f / 32767.0f);                 \
        union { uint2 u; __half2 h2[2]; } U;                              \
        U.u = *(const uint2*)&y16[(size_t)c * D + fo];                    \
        float2 f0 = __half22float2(U.h2[0]);                              \
        float2 f1 = __half22float2(U.h2[1]);                              \
        a0 = fmaf(v, f0.x, a0); a1 = fmaf(v, f0.y, a1);                   \
        a2 = fmaf(v, f1.x, a2); a3 = fmaf(v, f1.y, a3);                   \
    }

    for (; e + 8 <= e1; e += 8) {
        unsigned int p = ev[e + g];
        GFMA(p);
    }
    if (e + g < e1) {
        unsigned int p = ev[e + g];
        GFMA(p);
    }
#undef GFMA

    // fold the 8 group partials (lanes differing in bits 3..5)
    a0 += __shfl_xor(a0, 8, 64);  a1 += __shfl_xor(a1, 8, 64);
    a2 += __shfl_xor(a2, 8, 64);  a3 += __shfl_xor(a3, 8, 64);
    a0 += __shfl_xor(a0, 16, 64); a1 += __shfl_xor(a1, 16, 64);
    a2 += __shfl_xor(a2, 16, 64); a3 += __shfl_xor(a3, 16, 64);
    a0 += __shfl_xor(a0, 32, 64); a1 += __shfl_xor(a1, 32, 64);
    a2 += __shfl_xor(a2, 32, 64); a3 += __shfl_xor(a3, 32, 64);

    if (g == 0) {
        float di = dinv[i];
        union { uint2 u; __half2 h2[2]; } S;
        S.u = *(const uint2*)&y16[(size_t)i * D + fo];
        float2 s0 = __half22float2(S.h2[0]);
        float2 s1 = __half22float2(S.h2[1]);
        float4 b = *(const float4*)&bias[fo];
        float o0 = b.x + di * (a0 + s0.x);
        float o1 = b.y + di * (a1 + s0.y);
        float o2 = b.z + di * (a2 + s1.x);
        float o3 = b.w + di * (a3 + s1.y);
        if (relu) {
            o0 = fmaxf(o0, 0.f); o1 = fmaxf(o1, 0.f);
            o2 = fmaxf(o2, 0.f); o3 = fmaxf(o3, 0.f);
        }
        union { uint2 u; __half2 h2[2]; } O;
        O.h2[0] = __float22half2_rn(make_float2(o0, o1));
        O.h2[1] = __float22half2_rn(make_float2(o2, o3));
        *(uint2*)&out16[(size_t)i * D + fo] = O.u;
    }
}

// ---------------------------------------------------------------------------
extern "C" void kernel_launch(void* const* d_in, const int* in_sizes, int n_in,
                              void* d_out, int out_size, void* d_ws, size_t ws_size,
                              hipStream_t stream) {
    const float* x  = (const float*)d_in[0];
    const int*   ei = (const int*)d_in[1];     // [2,E]: src row then dst row
    const float* ew = (const float*)d_in[2];
    const float* W1 = (const float*)d_in[3];
    const float* b1 = (const float*)d_in[4];
    const float* W2 = (const float*)d_in[5];
    const float* b2 = (const float*)d_in[6];
    const float* W3 = (const float*)d_in[7];
    const float* b3 = (const float*)d_in[8];
    const float* Wl = (const float*)d_in[9];
    const float* bl = (const float*)d_in[10];

    int N = in_sizes[0] / D;    // 50000
    int E = in_sizes[2];        // 800000

    char* ws = (char*)d_ws;
    size_t off = 0;
    auto alloc = [&](size_t bytes) {
        void* p = ws + off;
        off = (off + bytes + 255) & ~(size_t)255;
        return p;
    };
    unsigned int* cntp = (unsigned int*)alloc((size_t)N * CNT_STRIDE * 4); // 3.2 MB
    float*  dinv = (float*)alloc((size_t)N * 4);
    int*    bsum = (int*)  alloc(1024);
    int*    boff = (int*)  alloc(1024);
    int*    rp   = (int*)  alloc((size_t)(N + 1) * 4);
    int*    loc  = (int*)  alloc((size_t)E * 4);
    unsigned int* ev = (unsigned int*)alloc((size_t)E * 4);
    __half* y16  = (__half*)alloc((size_t)N * D * 2);
    __half* z16  = (__half*)alloc((size_t)N * D * 2);

    int nbN = (N + 255) / 256;      // 196 (<= 256 for k_scan_b)
    int nbE = (E + 255) / 256;

    hipMemsetAsync(cntp, 0, (size_t)N * CNT_STRIDE * 4, stream);
    k_edge_pass1<<<nbE, 256, 0, stream>>>(ei + E, cntp, loc, E);
    k_scan_a<<<nbN, 256, 0, stream>>>(cntp, bsum, N);
    k_scan_b<<<1, 256, 0, stream>>>(bsum, boff, nbN);
    k_scan_c<<<nbN, 256, 0, stream>>>(cntp, boff, rp, N, E);
    k_fill<<<nbE, 256, 0, stream>>>(ei, ew, rp, loc, ev, E);
    k_deg<<<nbN, 256, 0, stream>>>(rp, ev, dinv, N);

    int gg = (N + 127) / 128;       // 391 GEMM blocks
    int ga = ((N + 3) / 4) * 4;     // agg blocks: node-group x 4 slices

    k_gemm_mfma<true ><<<gg, 256, 0, stream>>>(x,   W1, dinv, nullptr, nullptr, y16, N);
    k_agg<<<ga, 256, 0, stream>>>(y16, rp, ev, dinv, b1, z16, N, 1);
    k_gemm_mfma<false><<<gg, 256, 0, stream>>>(z16, W2, dinv, nullptr, nullptr, y16, N);
    k_agg<<<ga, 256, 0, stream>>>(y16, rp, ev, dinv, b2, z16, N, 1);
    k_gemm_mfma<false><<<gg, 256, 0, stream>>>(z16, W3, dinv, nullptr, nullptr, y16, N);
    k_agg<<<ga, 256, 0, stream>>>(y16, rp, ev, dinv, b3, z16, N, 0);
    k_gemm_mfma<false><<<gg, 256, 0, stream>>>(z16, Wl, nullptr, bl, (float*)d_out, nullptr, N);
}

// Round 9
// 300.801 us; speedup vs baseline: 1.4902x; 1.4902x over previous
//
#include <hip/hip_runtime.h>
#include <hip/hip_fp16.h>

// ---------------------------------------------------------------------------
// 3-layer GCN + linear head.  N=50000 nodes, E=800000 edges, D=128.
// Normalization factored: GEMM writes y16 = dinv*(z@W); CSR stores raw w
// (4 B packed); agg: out = b + dinv_i*(y16_i + sum w*y16_src).
// Aggregation: one wave per node, quarter-wave (16 lanes) per edge, full-row
// uint4 fp16 gathers, bounds-PREDICATED main loop (no low-MLP tail: invalid
// slots clamp to ev[e0] with weight 0, keeping 4 gathers/lane in flight).
// [Round-8 lesson: feature-slicing for XCD-L2 affinity cut FETCH but 4x'd
//  issue count -> 81 us; full-row at ~20% VALU is the right operating point.]
// ---------------------------------------------------------------------------

#define D 128

typedef __attribute__((ext_vector_type(8))) _Float16 half8;
typedef __attribute__((ext_vector_type(4))) float floatx4;

#define CNT_STRIDE 16   // one u32 counter per 64 B cache line

// ---- pass 1: count edges per dst; old count -> per-edge CSR slot ----------
__global__ __launch_bounds__(256) void k_edge_pass1(const int* __restrict__ dst,
                                                    unsigned int* __restrict__ cntp,
                                                    int* __restrict__ loc, int E) {
    int e = blockIdx.x * 256 + threadIdx.x;
    if (e < E) {
        int d = dst[e];
        loc[e] = (int)atomicAdd(&cntp[(size_t)d * CNT_STRIDE], 1u);
    }
}

// ---- block-wide exclusive scan helper (256 threads) -----------------------
__device__ inline int block_exscan_256(int v) {
    int tid = threadIdx.x;
    int lane = tid & 63, wv = tid >> 6;
    int incl = v;
#pragma unroll
    for (int d = 1; d < 64; d <<= 1) {
        int n = __shfl_up(incl, d, 64);
        if (lane >= d) incl += n;
    }
    __shared__ int wsum[4];
    if (lane == 63) wsum[wv] = incl;
    __syncthreads();
    int woff = 0;
#pragma unroll
    for (int j = 0; j < 4; j++) woff += (j < wv) ? wsum[j] : 0;
    return woff + incl - v;
}

__global__ __launch_bounds__(256) void k_scan_a(const unsigned int* __restrict__ cntp,
                                                int* bsum, int N) {
    int i = blockIdx.x * 256 + threadIdx.x;
    int v = (i < N) ? (int)cntp[(size_t)i * CNT_STRIDE] : 0;
#pragma unroll
    for (int d = 32; d; d >>= 1) v += __shfl_down(v, d, 64);
    __shared__ int ws4[4];
    int lane = threadIdx.x & 63, wv = threadIdx.x >> 6;
    if (lane == 0) ws4[wv] = v;
    __syncthreads();
    if (threadIdx.x == 0) bsum[blockIdx.x] = ws4[0] + ws4[1] + ws4[2] + ws4[3];
}

__global__ __launch_bounds__(256) void k_scan_b(const int* __restrict__ bsum,
                                                int* boff, int nb) {
    int tid = threadIdx.x;
    int v = (tid < nb) ? bsum[tid] : 0;
    int ex = block_exscan_256(v);
    if (tid < nb) boff[tid] = ex;
}

__global__ __launch_bounds__(256) void k_scan_c(const unsigned int* __restrict__ cntp,
                                                const int* __restrict__ boff,
                                                int* rp, int N, int E) {
    int i = blockIdx.x * 256 + threadIdx.x;
    int v = (i < N) ? (int)cntp[(size_t)i * CNT_STRIDE] : 0;
    int ex = block_exscan_256(v);
    if (i < N) rp[i] = boff[blockIdx.x] + ex;
    if (i == 0) rp[N] = E;
}

// ---- CSR fill: ev[p] = (w_q15 << 17) | src  (4 B per edge, no gathers) ----
__global__ __launch_bounds__(256) void k_fill(const int* __restrict__ ei,
                                              const float* __restrict__ w,
                                              const int* __restrict__ rp,
                                              const int* __restrict__ loc,
                                              unsigned int* __restrict__ ev, int E) {
    int e = blockIdx.x * 256 + threadIdx.x;
    if (e < E) {
        int s = ei[e];
        int d = ei[E + e];
        int p = rp[d] + loc[e];
        unsigned int wq = (unsigned int)__float2uint_rn(w[e] * 32767.0f);
        ev[p] = (wq << 17) | (unsigned int)s;
    }
}

// ---- weighted degree from CSR; dinv = rsqrt(1 + sum w) --------------------
__global__ __launch_bounds__(256) void k_deg(const int* __restrict__ rp,
                                             const unsigned int* __restrict__ ev,
                                             float* __restrict__ dinv, int N) {
    int i = blockIdx.x * 256 + threadIdx.x;
    if (i < N) {
        int e0 = rp[i], e1 = rp[i + 1];
        float s = 0.f;
        for (int e = e0; e < e1; e++)
            s += (float)(ev[e] >> 17);
        dinv[i] = rsqrtf(1.0f + s * (1.0f / 32767.0f));
    }
}

// ---- MFMA GEMM: y = A @ W ; optional row scale by dinv; optional bias -----
// 128 rows/block (4 waves x 32 rows), v_mfma_f32_16x16x32_f16, fp32 accum.
// W staged transposed as fp16 in LDS (Wl[n][k], pad->136). A fragments from
// global (read exactly once). Layouts (m89/m91): A[m=lane&15][k=quad*8+j],
// B[k=quad*8+j][n=lane&15], C/D col=lane&15, row=quad*4+reg.
template <bool A_IS_F32>
__global__ __launch_bounds__(256) void k_gemm_mfma(const void* __restrict__ Aptr,
                                                   const float* __restrict__ W,
                                                   const float* __restrict__ dinv,
                                                   const float* __restrict__ bias,
                                                   float* __restrict__ C32,
                                                   __half* __restrict__ C16, int N) {
    __shared__ _Float16 Wl[128][136];
    int tid = threadIdx.x;

#pragma unroll
    for (int j = 0; j < 64; j++) {
        int e = tid + j * 256;          // 16384 elements
        int k = e >> 7, n = e & 127;
        Wl[n][k] = (_Float16)W[e];
    }
    __syncthreads();

    int wave = tid >> 6, lane = tid & 63;
    int m = lane & 15, q = lane >> 4;
    int R0 = blockIdx.x * 128 + wave * 32;   // row tiles R0, R0+16

    const float*  A32p = (const float*)Aptr;
    const __half* A16p = (const __half*)Aptr;

    floatx4 acc[2][8];
#pragma unroll
    for (int rt = 0; rt < 2; rt++)
#pragma unroll
        for (int ct = 0; ct < 8; ct++) acc[rt][ct] = (floatx4){0.f, 0.f, 0.f, 0.f};

#pragma unroll
    for (int kk = 0; kk < 4; kk++) {
        half8 a[2];
#pragma unroll
        for (int rt = 0; rt < 2; rt++) {
            int row = R0 + rt * 16 + m;
            half8 t = {0, 0, 0, 0, 0, 0, 0, 0};
            if (row < N) {
                if (A_IS_F32) {
                    const float* p = &A32p[(size_t)row * 128 + kk * 32 + q * 8];
                    float4 f0 = *(const float4*)p;
                    float4 f1 = *(const float4*)(p + 4);
                    t[0] = (_Float16)f0.x; t[1] = (_Float16)f0.y;
                    t[2] = (_Float16)f0.z; t[3] = (_Float16)f0.w;
                    t[4] = (_Float16)f1.x; t[5] = (_Float16)f1.y;
                    t[6] = (_Float16)f1.z; t[7] = (_Float16)f1.w;
                } else {
                    t = *(const half8*)&A16p[(size_t)row * 128 + kk * 32 + q * 8];
                }
            }
            a[rt] = t;
        }
#pragma unroll
        for (int ct = 0; ct < 8; ct++) {
            half8 b = *(const half8*)&Wl[ct * 16 + m][kk * 32 + q * 8];
            acc[0][ct] = __builtin_amdgcn_mfma_f32_16x16x32_f16(a[0], b, acc[0][ct], 0, 0, 0);
            acc[1][ct] = __builtin_amdgcn_mfma_f32_16x16x32_f16(a[1], b, acc[1][ct], 0, 0, 0);
        }
    }

    // epilogue: C/D col=lane&15 (=m), row=quad*4+reg
#pragma unroll
    for (int rt = 0; rt < 2; rt++) {
#pragma unroll
        for (int r = 0; r < 4; r++) {
            int row = R0 + rt * 16 + q * 4 + r;
            if (row >= N) continue;
            float dv = (dinv != nullptr) ? dinv[row] : 1.0f;
#pragma unroll
            for (int ct = 0; ct < 8; ct++) {
                int col = ct * 16 + m;
                float v = acc[rt][ct][r] * dv;
                if (C16) C16[(size_t)row * 128 + col] = __float2half_rn(v);
                if (C32) C32[(size_t)row * 128 + col] = v + bias[col];
            }
        }
    }
}

// ---- aggregation: out_i = b + dinv_i*(y16_i + sum w*y16_src) --------------
// One wave per node; quarter-wave (16 lanes) per edge slot; lane sl=lane&15
// covers features sl*8..sl*8+7 as one uint4 (8 fp16). The main loop is
// bounds-PREDICATED: every iteration issues 4 ev loads + 4 row gathers per
// lane regardless of degree (invalid slots clamp to ev[e0], weight 0).
__global__ __launch_bounds__(256) void k_agg(const __half* __restrict__ y16,
                                             const int* __restrict__ rp,
                                             const unsigned int* __restrict__ ev,
                                             const float* __restrict__ dinv,
                                             const float* __restrict__ bias,
                                             __half* __restrict__ out16,
                                             int N, int relu) {
    int i = blockIdx.x * 4 + (threadIdx.x >> 6);
    if (i >= N) return;
    int lane = threadIdx.x & 63;
    int g = lane >> 4;
    int sl = lane & 15;

    float acc[8];
#pragma unroll
    for (int j = 0; j < 8; j++) acc[j] = 0.f;

    int e0 = rp[i], e1 = rp[i + 1];

    for (int e = e0; e < e1; e += 16) {
        unsigned int p[4];
        float v[4];
        uint4 q[4];
#pragma unroll
        for (int u = 0; u < 4; u++) {
            int idx = e + u * 4 + g;
            bool ok = idx < e1;
            p[u] = ev[ok ? idx : e0];
            v[u] = ok ? (float)(p[u] >> 17) * (1.0f / 32767.0f) : 0.0f;
        }
#pragma unroll
        for (int u = 0; u < 4; u++)
            q[u] = *(const uint4*)&y16[(size_t)(p[u] & 0x1FFFFu) * D + sl * 8];
#pragma unroll
        for (int u = 0; u < 4; u++) {
            union { uint4 uu; __half2 h2[4]; } U; U.uu = q[u];
            float2 f0 = __half22float2(U.h2[0]);
            float2 f1 = __half22float2(U.h2[1]);
            float2 f2 = __half22float2(U.h2[2]);
            float2 f3 = __half22float2(U.h2[3]);
            acc[0] = fmaf(v[u], f0.x, acc[0]); acc[1] = fmaf(v[u], f0.y, acc[1]);
            acc[2] = fmaf(v[u], f1.x, acc[2]); acc[3] = fmaf(v[u], f1.y, acc[3]);
            acc[4] = fmaf(v[u], f2.x, acc[4]); acc[5] = fmaf(v[u], f2.y, acc[5]);
            acc[6] = fmaf(v[u], f3.x, acc[6]); acc[7] = fmaf(v[u], f3.y, acc[7]);
        }
    }

    // fold the 4 quarter-wave partials (lane ^16, ^32)
#pragma unroll
    for (int j = 0; j < 8; j++) {
        acc[j] += __shfl_xor(acc[j], 16, 64);
        acc[j] += __shfl_xor(acc[j], 32, 64);
    }

    if (g == 0) {
        float di = dinv[i];
        union { uint4 u; __half2 h2[4]; } S;
        S.u = *(const uint4*)&y16[(size_t)i * D + sl * 8];
        float2 s0 = __half22float2(S.h2[0]);
        float2 s1 = __half22float2(S.h2[1]);
        float2 s2 = __half22float2(S.h2[2]);
        float2 s3 = __half22float2(S.h2[3]);
        float4 b0 = *(const float4*)&bias[sl * 8];
        float4 b1 = *(const float4*)&bias[sl * 8 + 4];
        float o[8];
        o[0] = b0.x + di * (acc[0] + s0.x);
        o[1] = b0.y + di * (acc[1] + s0.y);
        o[2] = b0.z + di * (acc[2] + s1.x);
        o[3] = b0.w + di * (acc[3] + s1.y);
        o[4] = b1.x + di * (acc[4] + s2.x);
        o[5] = b1.y + di * (acc[5] + s2.y);
        o[6] = b1.z + di * (acc[6] + s3.x);
        o[7] = b1.w + di * (acc[7] + s3.y);
        if (relu) {
#pragma unroll
            for (int j = 0; j < 8; j++) o[j] = fmaxf(o[j], 0.f);
        }
        union { uint4 u; __half2 h2[4]; } O;
        O.h2[0] = __float22half2_rn(make_float2(o[0], o[1]));
        O.h2[1] = __float22half2_rn(make_float2(o[2], o[3]));
        O.h2[2] = __float22half2_rn(make_float2(o[4], o[5]));
        O.h2[3] = __float22half2_rn(make_float2(o[6], o[7]));
        *(uint4*)&out16[(size_t)i * D + sl * 8] = O.u;
    }
}

// ---------------------------------------------------------------------------
extern "C" void kernel_launch(void* const* d_in, const int* in_sizes, int n_in,
                              void* d_out, int out_size, void* d_ws, size_t ws_size,
                              hipStream_t stream) {
    const float* x  = (const float*)d_in[0];
    const int*   ei = (const int*)d_in[1];     // [2,E]: src row then dst row
    const float* ew = (const float*)d_in[2];
    const float* W1 = (const float*)d_in[3];
    const float* b1 = (const float*)d_in[4];
    const float* W2 = (const float*)d_in[5];
    const float* b2 = (const float*)d_in[6];
    const float* W3 = (const float*)d_in[7];
    const float* b3 = (const float*)d_in[8];
    const float* Wl = (const float*)d_in[9];
    const float* bl = (const float*)d_in[10];

    int N = in_sizes[0] / D;    // 50000
    int E = in_sizes[2];        // 800000

    char* ws = (char*)d_ws;
    size_t off = 0;
    auto alloc = [&](size_t bytes) {
        void* p = ws + off;
        off = (off + bytes + 255) & ~(size_t)255;
        return p;
    };
    unsigned int* cntp = (unsigned int*)alloc((size_t)N * CNT_STRIDE * 4); // 3.2 MB
    float*  dinv = (float*)alloc((size_t)N * 4);
    int*    bsum = (int*)  alloc(1024);
    int*    boff = (int*)  alloc(1024);
    int*    rp   = (int*)  alloc((size_t)(N + 1) * 4);
    int*    loc  = (int*)  alloc((size_t)E * 4);
    unsigned int* ev = (unsigned int*)alloc((size_t)E * 4);
    __half* y16  = (__half*)alloc((size_t)N * D * 2);
    __half* z16  = (__half*)alloc((size_t)N * D * 2);

    int nbN = (N + 255) / 256;      // 196 (<= 256 for k_scan_b)
    int nbE = (E + 255) / 256;

    hipMemsetAsync(cntp, 0, (size_t)N * CNT_STRIDE * 4, stream);
    k_edge_pass1<<<nbE, 256, 0, stream>>>(ei + E, cntp, loc, E);
    k_scan_a<<<nbN, 256, 0, stream>>>(cntp, bsum, N);
    k_scan_b<<<1, 256, 0, stream>>>(bsum, boff, nbN);
    k_scan_c<<<nbN, 256, 0, stream>>>(cntp, boff, rp, N, E);
    k_fill<<<nbE, 256, 0, stream>>>(ei, ew, rp, loc, ev, E);
    k_deg<<<nbN, 256, 0, stream>>>(rp, ev, dinv, N);

    int gg = (N + 127) / 128;   // 391 GEMM blocks
    int ga = (N + 3) / 4;       // agg blocks (4 waves each)

    k_gemm_mfma<true ><<<gg, 256, 0, stream>>>(x,   W1, dinv, nullptr, nullptr, y16, N);
    k_agg<<<ga, 256, 0, stream>>>(y16, rp, ev, dinv, b1, z16, N, 1);
    k_gemm_mfma<false><<<gg, 256, 0, stream>>>(z16, W2, dinv, nullptr, nullptr, y16, N);
    k_agg<<<ga, 256, 0, stream>>>(y16, rp, ev, dinv, b2, z16, N, 1);
    k_gemm_mfma<false><<<gg, 256, 0, stream>>>(z16, W3, dinv, nullptr, nullptr, y16, N);
    k_agg<<<ga, 256, 0, stream>>>(y16, rp, ev, dinv, b3, z16, N, 0);
    k_gemm_mfma<false><<<gg, 256, 0, stream>>>(z16, Wl, nullptr, bl, (float*)d_out, nullptr, N);
}